// Round 7
// baseline (170.358 us; speedup 1.0000x reference)
//
#include <hip/hip_runtime.h>
#include <math.h>

namespace {
constexpr int K = 16, T = 8, R = 8, NB = 32;
constexpr int NX = 64, NY = 64, NZ = 32;
constexpr int NVOX = NX * NY * NZ;                 // 131072
constexpr float TWO_PI_OVER_C = (float)(6.283185307179586 / 299792458.0);
constexpr float CT_SCALE = 4.0f / 256.0f;          // folded 4 and 1/65536 split across Ht,Hr
constexpr float CR_SCALE = 1.0f / 256.0f;          // total scale = 4/65536; cancels in normalize
// B table: [tr(64)][frag(3: yRe,yIm,-yIm)][kc(2)][n(32)][j(8)] halves = 196608 B
constexpr int B_HALVES = 64 * 3 * 2 * 32 * 8;      // 98304
constexpr size_t WS_NEED = 256 + (size_t)B_HALVES * 2;
}

typedef _Float16 half8 __attribute__((ext_vector_type(8)));
typedef __fp16 fp16x2 __attribute__((ext_vector_type(2)));   // cvt_pkrtz native type
typedef float f32x16 __attribute__((ext_vector_type(16)));

// ---------------------------------------------------------------------------
// Prep: zero max slot; build B fragments in ws for the 32x32x16 layout.
// B[k][n] per (tr, frag): frag 0 = yRe, 1 = yIm, 2 = -yIm; k = kc*8 + j.
// halves index = (((tr*3 + f)*2 + kc)*32 + n)*8 + j  == id*8 + j.
// ---------------------------------------------------------------------------
__global__ void prep_kernel(const float* __restrict__ yr, const float* __restrict__ yi,
                            _Float16* __restrict__ wsB, unsigned int* __restrict__ maxslot,
                            int use_ws) {
    int id = blockIdx.x * 256 + threadIdx.x;   // 12288 tasks
    if (id == 0) *maxslot = 0u;
    if (!use_ws || id >= 64 * 3 * 2 * 32) return;
    int n    = id & 31;
    int rest = id >> 5;            // (tr*3 + f)*2 + kc
    int kc   = rest & 1;
    int ftr  = rest >> 1;          // tr*3 + f
    int f    = ftr % 3;
    int tr   = ftr / 3;
    int t = tr >> 3, r = tr & 7;
    const float* src = (f == 0) ? yr : yi;
    float sg = (f == 2) ? -1.0f : 1.0f;
    int base = n * (K * T * R) + (kc * 8) * (T * R) + t * R + r;
    half8 h;
#pragma unroll
    for (int j = 0; j < 8; ++j)
        h[j] = (_Float16)(sg * src[base + j * (T * R)]);
    ((half8*)wsB)[id] = h;
}

// ---------------------------------------------------------------------------
// Main: per wave-PAIR, 32-voxel x 32-batch complex tile via mfma_f32_32x32x16.
// Round-6 structure (verified, 59 us) with ONE change: the t-loop is split
// across two waves (t=0..3 / t=4..7, 32 iterations each) and the partial
// complex sums are combined through an 8 KB LDS buffer. Grid doubles to
// 2048 blocks -> 6 blocks/CU resident (VGPR 76 allows 6 waves/SIMD, was 4)
// and each wave carries half as many latency chains: the kernel is ~84%
// SIMD-idle latency-bound, so TLP is the lever.
// A layout: row = lane&31 (voxel), k = (lane>>5)*8 + j (freq) -> Hr lane-
// local in registers; no LDS in the hot loop.
// C/D layout (HW-verified): col = lane&31 = n, row = (reg&3)+8*(reg>>2)+4*kc.
// ---------------------------------------------------------------------------
template <bool USE_WS>
__global__ __launch_bounds__(256, 4) void kirch_mfma(
    const float* __restrict__ freqs,
    const float* __restrict__ txp, const float* __restrict__ rxp,
    const float* __restrict__ xc, const float* __restrict__ yc, const float* __restrict__ zc,
    const _Float16* __restrict__ wsB,
    const float* __restrict__ yr, const float* __restrict__ yi,
    float* __restrict__ out, unsigned int* __restrict__ maxslot)
{
    __shared__ float sAcc[2][16][64];          // 8 KB cross-wave combine buffer

    const int tid  = threadIdx.x;
    const int lane = tid & 63;
    const int wave = tid >> 6;
    const int pair = wave >> 1;                // 0..1: which 32-voxel tile
    const int half = wave & 1;                 // 0: t=0..3, 1: t=4..7
    const int ml   = lane & 31;                // voxel row (A) / batch col (B,C)
    const int kc   = lane >> 5;                // freq-half select
    const int vb   = blockIdx.x * 64 + pair * 32;
    const int v    = vb + ml;                  // this lane's voxel

    const float k0 = TWO_PI_OVER_C * freqs[0];
    const float dk = TWO_PI_OVER_C * (freqs[K - 1] - freqs[0]) * (1.0f / (K - 1));
    const float kstart = k0 + (float)(kc * 8) * dk;

    const float px = xc[v >> 11];
    const float py = yc[(v >> 5) & 63];
    const float pz = zc[v & 31];

    // H generator: 8-freq recurrence starting at kstart for element at (sx,sy,sz).
    auto computeH = [&](float sx, float sy, float sz, float scale, half8& oRe, half8& oIm) {
        const float dx = px - sx, dy = py - sy, dz = pz - sz;
        const float Rr = sqrtf(dx * dx + dy * dy + dz * dz);
        const float c = scale * dz * __builtin_amdgcn_rcpf(Rr);
        float sph, cph, swp, cwp;
        __sincosf(kstart * Rr, &sph, &cph);
        __sincosf(dk * Rr, &swp, &cwp);
        float ur = cph, ui = sph;
        float ck = c * (kstart * Rr);
        const float dck = c * (dk * Rr);
        float hre[8], him[8];
#pragma unroll
        for (int j = 0; j < 8; ++j) {
            hre[j] = fmaf(c, ur, -(ck * ui));   // c*(ur - kR*ui)
            him[j] = fmaf(c, ui,  (ck * ur));   // c*(ui + kR*ur)
            if (j < 7) {
                float nr = fmaf(ur, cwp, -(ui * swp));
                ui = fmaf(ur, swp, ui * cwp);
                ur = nr;
                ck += dck;
            }
        }
        union { half8 v8; fp16x2 v2[4]; } uRe, uIm;
#pragma unroll
        for (int i = 0; i < 4; ++i) {
            uRe.v2[i] = __builtin_amdgcn_cvt_pkrtz(hre[2 * i], hre[2 * i + 1]);
            uIm.v2[i] = __builtin_amdgcn_cvt_pkrtz(him[2 * i], him[2 * i + 1]);
        }
        oRe = uRe.v8;
        oIm = uIm.v8;
    };

    // ---- prologue: Hr for all 8 rx elements, register-resident ----
    half8 hrRe[8], hrIm[8];
#pragma unroll
    for (int r = 0; r < 8; ++r)
        computeH(rxp[r * 3 + 0], rxp[r * 3 + 1], rxp[r * 3 + 2], CR_SCALE, hrRe[r], hrIm[r]);

    f32x16 accRe = {0,0,0,0,0,0,0,0,0,0,0,0,0,0,0,0};
    f32x16 accIm = {0,0,0,0,0,0,0,0,0,0,0,0,0,0,0,0};

    const int tr0 = half * 32;                 // this wave's first (t,r) pair
    const char* bbase = (const char*)wsB + (size_t)tr0 * 3072 + kc * 512 + ml * 16;

    // B fragments, double-buffered; frag offsets within a tr-slot (3072 B):
    // yRe @ +0, yIm @ +1024, -yIm @ +2048.
    half8 bRe[2], bIm[2], bNi[2];
    auto loadB = [&](int buf, int it) {
        if constexpr (USE_WS) {
            const char* bp = bbase + it * 3072;
            bRe[buf] = *(const half8*)(bp);
            bIm[buf] = *(const half8*)(bp + 1024);
            bNi[buf] = *(const half8*)(bp + 2048);
        } else {
            int tr = tr0 + it;
            int t = tr >> 3, r = tr & 7;
            int base = ml * (K * T * R) + (kc * 8) * (T * R) + t * R + r;
            half8 a, b, c2;
#pragma unroll
            for (int j = 0; j < 8; ++j) {
                float vre = yr[base + j * (T * R)];
                float vim = yi[base + j * (T * R)];
                a[j]  = (_Float16)vre;
                b[j]  = (_Float16)vim;
                c2[j] = (_Float16)(-vim);
            }
            bRe[buf] = a; bIm[buf] = b; bNi[buf] = c2;
        }
    };

    // ---- pipeline prologue ----
    half8 htRe[2], htIm[2];
    {
        const int t0 = half * 4;
        computeH(txp[t0 * 3 + 0], txp[t0 * 3 + 1], txp[t0 * 3 + 2], CT_SCALE, htRe[0], htIm[0]);
    }
    loadB(0, 0);

    // ---- main loop: 32 (t,r) pairs, fully unrolled, static indices ----
#pragma unroll
    for (int it = 0; it < 32; ++it) {
        const int tl  = it >> 3;               // local t index 0..3 (compile-time)
        const int r   = it & 7;
        const int cur = it & 1;
        const int nxt = cur ^ 1;

        // prefetch next iteration's B fragments (L2-resident)
        if (it + 1 < 32) loadB(nxt, it + 1);
        // next t's Ht at the midpoint of this t's r-sweep (hides serial chain)
        if (r == 4 && tl < 3) {
            const int tn = half * 4 + tl + 1;
            computeH(txp[tn * 3 + 0], txp[tn * 3 + 1], txp[tn * 3 + 2],
                     CT_SCALE, htRe[(tl + 1) & 1], htIm[(tl + 1) & 1]);
        }

        // ---- A fragments: packed-fp16 complex products ----
        half8 hRe = htRe[tl & 1], hIm = htIm[tl & 1];
        half8 ARe = hRe * hrRe[r] - hIm * hrIm[r];
        half8 AIm = hRe * hrIm[r] + hIm * hrRe[r];

        accRe = __builtin_amdgcn_mfma_f32_32x32x16_f16(ARe, bRe[cur], accRe, 0, 0, 0);
        accIm = __builtin_amdgcn_mfma_f32_32x32x16_f16(ARe, bIm[cur], accIm, 0, 0, 0);
        accRe = __builtin_amdgcn_mfma_f32_32x32x16_f16(AIm, bNi[cur], accRe, 0, 0, 0);
        accIm = __builtin_amdgcn_mfma_f32_32x32x16_f16(AIm, bRe[cur], accIm, 0, 0, 0);
    }

    // ---- cross-wave combine: half-1 partials -> half-0 wave, Re then Im ----
    if (half == 1) {
#pragma unroll
        for (int e = 0; e < 16; ++e) sAcc[pair][e][lane] = accRe[e];
    }
    __syncthreads();
    if (half == 0) {
#pragma unroll
        for (int e = 0; e < 16; ++e) accRe[e] += sAcc[pair][e][lane];
    }
    __syncthreads();
    if (half == 1) {
#pragma unroll
        for (int e = 0; e < 16; ++e) sAcc[pair][e][lane] = accIm[e];
    }
    __syncthreads();
    if (half == 0) {
#pragma unroll
        for (int e = 0; e < 16; ++e) accIm[e] += sAcc[pair][e][lane];

        // ---- epilogue (half-0 waves only): magnitudes, float4 stores, max ----
        // C/D: n = ml, vox = vb + (reg&3) + 8*(reg>>2) + 4*kc
        float mx = 0.0f;
#pragma unroll
        for (int g = 0; g < 4; ++g) {
            float om[4];
#pragma unroll
            for (int e = 0; e < 4; ++e) {
                float re = accRe[4 * g + e], im = accIm[4 * g + e];
                float m = sqrtf(re * re + im * im);
                om[e] = m;
                mx = fmaxf(mx, m);
            }
            *(float4*)&out[ml * NVOX + vb + 8 * g + 4 * kc] = *(float4*)om;
        }
#pragma unroll
        for (int off = 32; off > 0; off >>= 1)
            mx = fmaxf(mx, __shfl_down(mx, off));
        if (lane == 0)
            atomicMax(maxslot, __float_as_uint(mx));   // all values >= 0
    }
}

// ---------------------------------------------------------------------------
// Normalize: out *= 1/max
// ---------------------------------------------------------------------------
__global__ void normalize_kernel(float* __restrict__ out,
                                 const unsigned int* __restrict__ maxslot, int n4) {
    int i = blockIdx.x * blockDim.x + threadIdx.x;
    float inv = 1.0f / __uint_as_float(*maxslot);
    if (i < n4) {
        float4* o = (float4*)out;
        float4 vv = o[i];
        vv.x *= inv; vv.y *= inv; vv.z *= inv; vv.w *= inv;
        o[i] = vv;
    }
}

extern "C" void kernel_launch(void* const* d_in, const int* in_sizes, int n_in,
                              void* d_out, int out_size, void* d_ws, size_t ws_size,
                              hipStream_t stream) {
    const float* freqs = (const float*)d_in[0];
    const float* txp   = (const float*)d_in[1];
    const float* rxp   = (const float*)d_in[2];
    const float* xc    = (const float*)d_in[3];
    const float* yc    = (const float*)d_in[4];
    const float* zc    = (const float*)d_in[5];
    const float* yr    = (const float*)d_in[6];
    const float* yi    = (const float*)d_in[7];
    float* out = (float*)d_out;

    unsigned int* maxslot = (unsigned int*)d_ws;
    _Float16* wsB = (_Float16*)((char*)d_ws + 256);
    const int use_ws = (ws_size >= WS_NEED) ? 1 : 0;

    prep_kernel<<<48, 256, 0, stream>>>(yr, yi, wsB, maxslot, use_ws);

    if (use_ws)
        kirch_mfma<true><<<NVOX / 64, 256, 0, stream>>>(
            freqs, txp, rxp, xc, yc, zc, wsB, yr, yi, out, maxslot);
    else
        kirch_mfma<false><<<NVOX / 64, 256, 0, stream>>>(
            freqs, txp, rxp, xc, yc, zc, wsB, yr, yi, out, maxslot);

    int n4 = out_size / 4;
    normalize_kernel<<<(n4 + 255) / 256, 256, 0, stream>>>(out, maxslot, n4);
}

// Round 8
// 141.429 us; speedup vs baseline: 1.2045x; 1.2045x over previous
//
#include <hip/hip_runtime.h>
#include <math.h>

namespace {
constexpr int K = 16, T = 8, R = 8, NB = 32;
constexpr int NX = 64, NY = 64, NZ = 32;
constexpr int NVOX = NX * NY * NZ;                 // 131072
constexpr float TWO_PI_OVER_C = (float)(6.283185307179586 / 299792458.0);
constexpr float CT_SCALE = 4.0f / 256.0f;          // folded 4 and 1/65536 split across Ht,Hr
constexpr float CR_SCALE = 1.0f / 256.0f;          // total scale = 4/65536; cancels in normalize
// B table: [tr(64)][frag(3: yRe,yIm,-yIm)][kc(2)][n(32)][j(8)] halves = 196608 B
constexpr int B_HALVES = 64 * 3 * 2 * 32 * 8;      // 98304
constexpr size_t WS_NEED = 256 + (size_t)B_HALVES * 2;
}

typedef _Float16 half8 __attribute__((ext_vector_type(8)));
typedef __fp16 fp16x2 __attribute__((ext_vector_type(2)));   // cvt_pkrtz native type
typedef float f32x16 __attribute__((ext_vector_type(16)));

// ---------------------------------------------------------------------------
// Prep: zero max slot; build B fragments in ws for the 32x32x16 layout.
// B[k][n] per (tr, frag): frag 0 = yRe, 1 = yIm, 2 = -yIm; k = kc*8 + j.
// halves index = (((tr*3 + f)*2 + kc)*32 + n)*8 + j  == id*8 + j.
// ---------------------------------------------------------------------------
__global__ void prep_kernel(const float* __restrict__ yr, const float* __restrict__ yi,
                            _Float16* __restrict__ wsB, unsigned int* __restrict__ maxslot,
                            int use_ws) {
    int id = blockIdx.x * 256 + threadIdx.x;   // 12288 tasks
    if (id == 0) *maxslot = 0u;
    if (!use_ws || id >= 64 * 3 * 2 * 32) return;
    int n    = id & 31;
    int rest = id >> 5;            // (tr*3 + f)*2 + kc
    int kc   = rest & 1;
    int ftr  = rest >> 1;          // tr*3 + f
    int f    = ftr % 3;
    int tr   = ftr / 3;
    int t = tr >> 3, r = tr & 7;
    const float* src = (f == 0) ? yr : yi;
    float sg = (f == 2) ? -1.0f : 1.0f;
    int base = n * (K * T * R) + (kc * 8) * (T * R) + t * R + r;
    half8 h;
#pragma unroll
    for (int j = 0; j < 8; ++j)
        h[j] = (_Float16)(sg * src[base + j * (T * R)]);
    ((half8*)wsB)[id] = h;
}

// ---------------------------------------------------------------------------
// Main: per wave, 32-voxel x 32-batch complex tile via mfma_f32_32x32x16_f16.
// Round-6 verified structure (59 us): lane-local Hr in registers, no LDS in
// the hot loop, one voxel per lane (A row = lane&31, k = (lane>>5)*8+j).
// Round-8 adds (each independently removable):
//   (1) depth-2 B prefetch (triple buffer, issue it+2) — covers the ~200-300
//       cycle L2 chain with ~2 iterations of work instead of 1.
//   (2) s_setprio(1) around the MFMA cluster — independent-wave regime where
//       this measured +4-7%.
// launch_bounds stays (256,3): VGPR cap 170 >> ~120 live; NEVER tighten the
// cap below live-state (round-7 spill disaster).
// C/D layout (HW-verified): col = lane&31 = n, row = (reg&3)+8*(reg>>2)+4*kc.
// ---------------------------------------------------------------------------
template <bool USE_WS>
__global__ __launch_bounds__(256, 3) void kirch_mfma(
    const float* __restrict__ freqs,
    const float* __restrict__ txp, const float* __restrict__ rxp,
    const float* __restrict__ xc, const float* __restrict__ yc, const float* __restrict__ zc,
    const _Float16* __restrict__ wsB,
    const float* __restrict__ yr, const float* __restrict__ yi,
    float* __restrict__ out, unsigned int* __restrict__ maxslot)
{
    __shared__ float s_wmax[4];

    const int tid  = threadIdx.x;
    const int lane = tid & 63;
    const int wave = tid >> 6;
    const int ml   = lane & 31;                // voxel row (A) / batch col (B,C)
    const int kc   = lane >> 5;                // freq-half select
    const int vb   = blockIdx.x * 128 + wave * 32;
    const int v    = vb + ml;                  // this lane's voxel

    const float k0 = TWO_PI_OVER_C * freqs[0];
    const float dk = TWO_PI_OVER_C * (freqs[K - 1] - freqs[0]) * (1.0f / (K - 1));
    const float kstart = k0 + (float)(kc * 8) * dk;

    const float px = xc[v >> 11];
    const float py = yc[(v >> 5) & 63];
    const float pz = zc[v & 31];

    // H generator: 8-freq recurrence starting at kstart for element at (sx,sy,sz).
    auto computeH = [&](float sx, float sy, float sz, float scale, half8& oRe, half8& oIm) {
        const float dx = px - sx, dy = py - sy, dz = pz - sz;
        const float Rr = sqrtf(dx * dx + dy * dy + dz * dz);
        const float c = scale * dz * __builtin_amdgcn_rcpf(Rr);
        float sph, cph, swp, cwp;
        __sincosf(kstart * Rr, &sph, &cph);
        __sincosf(dk * Rr, &swp, &cwp);
        float ur = cph, ui = sph;
        float ck = c * (kstart * Rr);
        const float dck = c * (dk * Rr);
        float hre[8], him[8];
#pragma unroll
        for (int j = 0; j < 8; ++j) {
            hre[j] = fmaf(c, ur, -(ck * ui));   // c*(ur - kR*ui)
            him[j] = fmaf(c, ui,  (ck * ur));   // c*(ui + kR*ur)
            if (j < 7) {
                float nr = fmaf(ur, cwp, -(ui * swp));
                ui = fmaf(ur, swp, ui * cwp);
                ur = nr;
                ck += dck;
            }
        }
        union { half8 v8; fp16x2 v2[4]; } uRe, uIm;
#pragma unroll
        for (int i = 0; i < 4; ++i) {
            uRe.v2[i] = __builtin_amdgcn_cvt_pkrtz(hre[2 * i], hre[2 * i + 1]);
            uIm.v2[i] = __builtin_amdgcn_cvt_pkrtz(him[2 * i], him[2 * i + 1]);
        }
        oRe = uRe.v8;
        oIm = uIm.v8;
    };

    // ---- prologue: Hr for all 8 rx elements, register-resident ----
    half8 hrRe[8], hrIm[8];
#pragma unroll
    for (int r = 0; r < 8; ++r)
        computeH(rxp[r * 3 + 0], rxp[r * 3 + 1], rxp[r * 3 + 2], CR_SCALE, hrRe[r], hrIm[r]);

    f32x16 accRe = {0,0,0,0,0,0,0,0,0,0,0,0,0,0,0,0};
    f32x16 accIm = {0,0,0,0,0,0,0,0,0,0,0,0,0,0,0,0};

    const char* bbase = (const char*)wsB + kc * 512 + ml * 16;

    // B fragments, TRIPLE-buffered (depth-2 prefetch). frag byte offsets
    // within a tr-slot (3072 B): yRe @ +0, yIm @ +1024, -yIm @ +2048.
    half8 bRe[3], bIm[3], bNi[3];
    auto loadB = [&](int buf, int tr) {
        if constexpr (USE_WS) {
            const char* bp = bbase + tr * 3072;
            bRe[buf] = *(const half8*)(bp);
            bIm[buf] = *(const half8*)(bp + 1024);
            bNi[buf] = *(const half8*)(bp + 2048);
        } else {
            int t = tr >> 3, r = tr & 7;
            int base = ml * (K * T * R) + (kc * 8) * (T * R) + t * R + r;
            half8 a, b, c2;
#pragma unroll
            for (int j = 0; j < 8; ++j) {
                float vre = yr[base + j * (T * R)];
                float vim = yi[base + j * (T * R)];
                a[j]  = (_Float16)vre;
                b[j]  = (_Float16)vim;
                c2[j] = (_Float16)(-vim);
            }
            bRe[buf] = a; bIm[buf] = b; bNi[buf] = c2;
        }
    };

    // ---- pipeline prologue ----
    half8 htRe[2], htIm[2];
    computeH(txp[0], txp[1], txp[2], CT_SCALE, htRe[0], htIm[0]);
    loadB(0, 0);
    loadB(1, 1);

    // ---- main loop: 64 (t,r) pairs, fully unrolled, static indices ----
#pragma unroll
    for (int it = 0; it < 64; ++it) {
        const int t   = it >> 3;
        const int r   = it & 7;
        const int cur = it % 3;
        const int nxt = (it + 2) % 3;

        // prefetch B fragments TWO iterations ahead (L2 latency cover)
        if (it + 2 < 64) loadB(nxt, it + 2);
        // next t's Ht at the midpoint of this t's r-sweep (hides serial chain)
        if (r == 4 && t < 7)
            computeH(txp[(t + 1) * 3 + 0], txp[(t + 1) * 3 + 1], txp[(t + 1) * 3 + 2],
                     CT_SCALE, htRe[(t + 1) & 1], htIm[(t + 1) & 1]);

        // ---- A fragments: packed-fp16 complex products ----
        half8 hRe = htRe[t & 1], hIm = htIm[t & 1];
        half8 ARe = hRe * hrRe[r] - hIm * hrIm[r];
        half8 AIm = hRe * hrIm[r] + hIm * hrRe[r];

        __builtin_amdgcn_s_setprio(1);
        accRe = __builtin_amdgcn_mfma_f32_32x32x16_f16(ARe, bRe[cur], accRe, 0, 0, 0);
        accIm = __builtin_amdgcn_mfma_f32_32x32x16_f16(ARe, bIm[cur], accIm, 0, 0, 0);
        accRe = __builtin_amdgcn_mfma_f32_32x32x16_f16(AIm, bNi[cur], accRe, 0, 0, 0);
        accIm = __builtin_amdgcn_mfma_f32_32x32x16_f16(AIm, bRe[cur], accIm, 0, 0, 0);
        __builtin_amdgcn_s_setprio(0);
    }

    // ---- epilogue: magnitudes, float4 stores, block max ----
    // C/D: n = ml, vox = vb + (reg&3) + 8*(reg>>2) + 4*kc  (reg&3 -> contiguous)
    float mx = 0.0f;
#pragma unroll
    for (int g = 0; g < 4; ++g) {
        float om[4];
#pragma unroll
        for (int e = 0; e < 4; ++e) {
            float re = accRe[4 * g + e], im = accIm[4 * g + e];
            float m = sqrtf(re * re + im * im);
            om[e] = m;
            mx = fmaxf(mx, m);
        }
        *(float4*)&out[ml * NVOX + vb + 8 * g + 4 * kc] = *(float4*)om;
    }
#pragma unroll
    for (int off = 32; off > 0; off >>= 1)
        mx = fmaxf(mx, __shfl_down(mx, off));
    if (lane == 0) s_wmax[wave] = mx;
    __syncthreads();
    if (tid == 0) {
        float bm = fmaxf(fmaxf(s_wmax[0], s_wmax[1]), fmaxf(s_wmax[2], s_wmax[3]));
        atomicMax(maxslot, __float_as_uint(bm));
    }
}

// ---------------------------------------------------------------------------
// Normalize: out *= 1/max
// ---------------------------------------------------------------------------
__global__ void normalize_kernel(float* __restrict__ out,
                                 const unsigned int* __restrict__ maxslot, int n4) {
    int i = blockIdx.x * blockDim.x + threadIdx.x;
    float inv = 1.0f / __uint_as_float(*maxslot);
    if (i < n4) {
        float4* o = (float4*)out;
        float4 vv = o[i];
        vv.x *= inv; vv.y *= inv; vv.z *= inv; vv.w *= inv;
        o[i] = vv;
    }
}

extern "C" void kernel_launch(void* const* d_in, const int* in_sizes, int n_in,
                              void* d_out, int out_size, void* d_ws, size_t ws_size,
                              hipStream_t stream) {
    const float* freqs = (const float*)d_in[0];
    const float* txp   = (const float*)d_in[1];
    const float* rxp   = (const float*)d_in[2];
    const float* xc    = (const float*)d_in[3];
    const float* yc    = (const float*)d_in[4];
    const float* zc    = (const float*)d_in[5];
    const float* yr    = (const float*)d_in[6];
    const float* yi    = (const float*)d_in[7];
    float* out = (float*)d_out;

    unsigned int* maxslot = (unsigned int*)d_ws;
    _Float16* wsB = (_Float16*)((char*)d_ws + 256);
    const int use_ws = (ws_size >= WS_NEED) ? 1 : 0;

    prep_kernel<<<48, 256, 0, stream>>>(yr, yi, wsB, maxslot, use_ws);

    if (use_ws)
        kirch_mfma<true><<<NVOX / 128, 256, 0, stream>>>(
            freqs, txp, rxp, xc, yc, zc, wsB, yr, yi, out, maxslot);
    else
        kirch_mfma<false><<<NVOX / 128, 256, 0, stream>>>(
            freqs, txp, rxp, xc, yc, zc, wsB, yr, yi, out, maxslot);

    int n4 = out_size / 4;
    normalize_kernel<<<(n4 + 255) / 256, 256, 0, stream>>>(out, maxslot, n4);
}

// Round 9
// 127.152 us; speedup vs baseline: 1.3398x; 1.1123x over previous
//
#include <hip/hip_runtime.h>
#include <math.h>

namespace {
constexpr int K = 16, T = 8, R = 8, NB = 32;
constexpr int NX = 64, NY = 64, NZ = 32;
constexpr int NVOX = NX * NY * NZ;                 // 131072
constexpr float TWO_PI_OVER_C = (float)(6.283185307179586 / 299792458.0);
constexpr float CT_SCALE = 4.0f / 256.0f;          // folded 4 and 1/65536 split across Ht,Hr
constexpr float CR_SCALE = 1.0f / 256.0f;          // total scale = 4/65536; cancels in normalize
// B table: [tr(64)][frag(2: yRe,yIm)][kc(2)][n(32)][j(8)] halves = 131072 B
constexpr int B_HALVES = 64 * 2 * 2 * 32 * 8;      // 65536
constexpr size_t WS_NEED = 256 + (size_t)B_HALVES * 2;
}

typedef _Float16 half8 __attribute__((ext_vector_type(8)));
typedef __fp16 fp16x2 __attribute__((ext_vector_type(2)));   // cvt_pkrtz native type
typedef float f32x16 __attribute__((ext_vector_type(16)));

// ---------------------------------------------------------------------------
// Prep: zero max slot; build B fragments in ws for the 32x32x16 layout.
// B[k][n] per (tr, frag): frag 0 = yRe, 1 = yIm; k = kc*8 + j.
// halves index = (((tr*2 + f)*2 + kc)*32 + n)*8 + j  == id*8 + j.
// (The -yIm fragment is gone: negation moved to the A side via sign-bit XOR.)
// ---------------------------------------------------------------------------
__global__ void prep_kernel(const float* __restrict__ yr, const float* __restrict__ yi,
                            _Float16* __restrict__ wsB, unsigned int* __restrict__ maxslot,
                            int use_ws) {
    int id = blockIdx.x * 256 + threadIdx.x;   // 8192 tasks
    if (id == 0) *maxslot = 0u;
    if (!use_ws || id >= 64 * 2 * 2 * 32) return;
    int n    = id & 31;
    int rest = id >> 5;            // (tr*2 + f)*2 + kc
    int kc   = rest & 1;
    int ftr  = rest >> 1;          // tr*2 + f
    int f    = ftr & 1;
    int tr   = ftr >> 1;
    int t = tr >> 3, r = tr & 7;
    const float* src = (f == 0) ? yr : yi;
    int base = n * (K * T * R) + (kc * 8) * (T * R) + t * R + r;
    half8 h;
#pragma unroll
    for (int j = 0; j < 8; ++j)
        h[j] = (_Float16)(src[base + j * (T * R)]);
    ((half8*)wsB)[id] = h;
}

// ---------------------------------------------------------------------------
// Main: per wave, 32-voxel x 32-batch complex tile via mfma_f32_32x32x16_f16.
// Round-6 verified structure (59 us): lane-local Hr in registers, no LDS in
// the hot loop, one voxel per lane (A row = lane&31, k = (lane>>5)*8+j).
// Round-9 change: depth-2 B prefetch at ZERO register cost — the -yIm
// fragment is replaced by negating AIm (4 v_xor of fp16 sign bits), so the
// triple buffer of 2 fragments (24 VGPRs) costs exactly what round-6's
// double buffer of 3 fragments did. Round-8's spill (FETCH 30MB/WRITE 74MB)
// came from +12 regs crossing the unified-file cap; this avoids it.
// setprio kept around the MFMA cluster (independent-wave regime, m191 +).
// launch_bounds (256,3): NEVER tighten the cap below live-state (round 7).
// C/D layout (HW-verified): col = lane&31 = n, row = (reg&3)+8*(reg>>2)+4*kc.
// ---------------------------------------------------------------------------
template <bool USE_WS>
__global__ __launch_bounds__(256, 3) void kirch_mfma(
    const float* __restrict__ freqs,
    const float* __restrict__ txp, const float* __restrict__ rxp,
    const float* __restrict__ xc, const float* __restrict__ yc, const float* __restrict__ zc,
    const _Float16* __restrict__ wsB,
    const float* __restrict__ yr, const float* __restrict__ yi,
    float* __restrict__ out, unsigned int* __restrict__ maxslot)
{
    __shared__ float s_wmax[4];

    const int tid  = threadIdx.x;
    const int lane = tid & 63;
    const int wave = tid >> 6;
    const int ml   = lane & 31;                // voxel row (A) / batch col (B,C)
    const int kc   = lane >> 5;                // freq-half select
    const int vb   = blockIdx.x * 128 + wave * 32;
    const int v    = vb + ml;                  // this lane's voxel

    const float k0 = TWO_PI_OVER_C * freqs[0];
    const float dk = TWO_PI_OVER_C * (freqs[K - 1] - freqs[0]) * (1.0f / (K - 1));
    const float kstart = k0 + (float)(kc * 8) * dk;

    const float px = xc[v >> 11];
    const float py = yc[(v >> 5) & 63];
    const float pz = zc[v & 31];

    // H generator: 8-freq recurrence starting at kstart for element at (sx,sy,sz).
    auto computeH = [&](float sx, float sy, float sz, float scale, half8& oRe, half8& oIm) {
        const float dx = px - sx, dy = py - sy, dz = pz - sz;
        const float Rr = sqrtf(dx * dx + dy * dy + dz * dz);
        const float c = scale * dz * __builtin_amdgcn_rcpf(Rr);
        float sph, cph, swp, cwp;
        __sincosf(kstart * Rr, &sph, &cph);
        __sincosf(dk * Rr, &swp, &cwp);
        float ur = cph, ui = sph;
        float ck = c * (kstart * Rr);
        const float dck = c * (dk * Rr);
        float hre[8], him[8];
#pragma unroll
        for (int j = 0; j < 8; ++j) {
            hre[j] = fmaf(c, ur, -(ck * ui));   // c*(ur - kR*ui)
            him[j] = fmaf(c, ui,  (ck * ur));   // c*(ui + kR*ur)
            if (j < 7) {
                float nr = fmaf(ur, cwp, -(ui * swp));
                ui = fmaf(ur, swp, ui * cwp);
                ur = nr;
                ck += dck;
            }
        }
        union { half8 v8; fp16x2 v2[4]; } uRe, uIm;
#pragma unroll
        for (int i = 0; i < 4; ++i) {
            uRe.v2[i] = __builtin_amdgcn_cvt_pkrtz(hre[2 * i], hre[2 * i + 1]);
            uIm.v2[i] = __builtin_amdgcn_cvt_pkrtz(him[2 * i], him[2 * i + 1]);
        }
        oRe = uRe.v8;
        oIm = uIm.v8;
    };

    // ---- prologue: Hr for all 8 rx elements, register-resident ----
    half8 hrRe[8], hrIm[8];
#pragma unroll
    for (int r = 0; r < 8; ++r)
        computeH(rxp[r * 3 + 0], rxp[r * 3 + 1], rxp[r * 3 + 2], CR_SCALE, hrRe[r], hrIm[r]);

    f32x16 accRe = {0,0,0,0,0,0,0,0,0,0,0,0,0,0,0,0};
    f32x16 accIm = {0,0,0,0,0,0,0,0,0,0,0,0,0,0,0,0};

    const char* bbase = (const char*)wsB + kc * 512 + ml * 16;

    // B fragments, TRIPLE-buffered (depth-2 prefetch), 2 frags only.
    // Byte offsets within a tr-slot (2048 B): yRe @ +0, yIm @ +1024.
    half8 bRe[3], bIm[3];
    auto loadB = [&](int buf, int tr) {
        if constexpr (USE_WS) {
            const char* bp = bbase + tr * 2048;
            bRe[buf] = *(const half8*)(bp);
            bIm[buf] = *(const half8*)(bp + 1024);
        } else {
            int t = tr >> 3, r = tr & 7;
            int base = ml * (K * T * R) + (kc * 8) * (T * R) + t * R + r;
            half8 a, b;
#pragma unroll
            for (int j = 0; j < 8; ++j) {
                a[j] = (_Float16)yr[base + j * (T * R)];
                b[j] = (_Float16)yi[base + j * (T * R)];
            }
            bRe[buf] = a; bIm[buf] = b;
        }
    };

    // ---- pipeline prologue ----
    half8 htRe[2], htIm[2];
    computeH(txp[0], txp[1], txp[2], CT_SCALE, htRe[0], htIm[0]);
    loadB(0, 0);
    loadB(1, 1);

    // ---- main loop: 64 (t,r) pairs, fully unrolled, static indices ----
#pragma unroll
    for (int it = 0; it < 64; ++it) {
        const int t   = it >> 3;
        const int r   = it & 7;
        const int cur = it % 3;
        const int nxt = (it + 2) % 3;

        // prefetch B fragments TWO iterations ahead (L2 latency cover)
        if (it + 2 < 64) loadB(nxt, it + 2);
        // next t's Ht at the midpoint of this t's r-sweep (hides serial chain)
        if (r == 4 && t < 7)
            computeH(txp[(t + 1) * 3 + 0], txp[(t + 1) * 3 + 1], txp[(t + 1) * 3 + 2],
                     CT_SCALE, htRe[(t + 1) & 1], htIm[(t + 1) & 1]);

        // ---- A fragments: packed-fp16 complex products ----
        half8 hRe = htRe[t & 1], hIm = htIm[t & 1];
        half8 ARe = hRe * hrRe[r] - hIm * hrIm[r];
        half8 AIm = hRe * hrIm[r] + hIm * hrRe[r];
        union { half8 h; unsigned int u[4]; } An;     // -AIm via sign-bit XOR
        An.h = AIm;
#pragma unroll
        for (int i = 0; i < 4; ++i) An.u[i] ^= 0x80008000u;

        __builtin_amdgcn_s_setprio(1);
        accRe = __builtin_amdgcn_mfma_f32_32x32x16_f16(ARe,  bRe[cur], accRe, 0, 0, 0);
        accIm = __builtin_amdgcn_mfma_f32_32x32x16_f16(ARe,  bIm[cur], accIm, 0, 0, 0);
        accRe = __builtin_amdgcn_mfma_f32_32x32x16_f16(An.h, bIm[cur], accRe, 0, 0, 0);
        accIm = __builtin_amdgcn_mfma_f32_32x32x16_f16(AIm,  bRe[cur], accIm, 0, 0, 0);
        __builtin_amdgcn_s_setprio(0);
    }

    // ---- epilogue: magnitudes, float4 stores, block max ----
    // C/D: n = ml, vox = vb + (reg&3) + 8*(reg>>2) + 4*kc  (reg&3 -> contiguous)
    float mx = 0.0f;
#pragma unroll
    for (int g = 0; g < 4; ++g) {
        float om[4];
#pragma unroll
        for (int e = 0; e < 4; ++e) {
            float re = accRe[4 * g + e], im = accIm[4 * g + e];
            float m = sqrtf(re * re + im * im);
            om[e] = m;
            mx = fmaxf(mx, m);
        }
        *(float4*)&out[ml * NVOX + vb + 8 * g + 4 * kc] = *(float4*)om;
    }
#pragma unroll
    for (int off = 32; off > 0; off >>= 1)
        mx = fmaxf(mx, __shfl_down(mx, off));
    if (lane == 0) s_wmax[wave] = mx;
    __syncthreads();
    if (tid == 0) {
        float bm = fmaxf(fmaxf(s_wmax[0], s_wmax[1]), fmaxf(s_wmax[2], s_wmax[3]));
        atomicMax(maxslot, __float_as_uint(bm));
    }
}

// ---------------------------------------------------------------------------
// Normalize: out *= 1/max
// ---------------------------------------------------------------------------
__global__ void normalize_kernel(float* __restrict__ out,
                                 const unsigned int* __restrict__ maxslot, int n4) {
    int i = blockIdx.x * blockDim.x + threadIdx.x;
    float inv = 1.0f / __uint_as_float(*maxslot);
    if (i < n4) {
        float4* o = (float4*)out;
        float4 vv = o[i];
        vv.x *= inv; vv.y *= inv; vv.z *= inv; vv.w *= inv;
        o[i] = vv;
    }
}

extern "C" void kernel_launch(void* const* d_in, const int* in_sizes, int n_in,
                              void* d_out, int out_size, void* d_ws, size_t ws_size,
                              hipStream_t stream) {
    const float* freqs = (const float*)d_in[0];
    const float* txp   = (const float*)d_in[1];
    const float* rxp   = (const float*)d_in[2];
    const float* xc    = (const float*)d_in[3];
    const float* yc    = (const float*)d_in[4];
    const float* zc    = (const float*)d_in[5];
    const float* yr    = (const float*)d_in[6];
    const float* yi    = (const float*)d_in[7];
    float* out = (float*)d_out;

    unsigned int* maxslot = (unsigned int*)d_ws;
    _Float16* wsB = (_Float16*)((char*)d_ws + 256);
    const int use_ws = (ws_size >= WS_NEED) ? 1 : 0;

    prep_kernel<<<32, 256, 0, stream>>>(yr, yi, wsB, maxslot, use_ws);

    if (use_ws)
        kirch_mfma<true><<<NVOX / 128, 256, 0, stream>>>(
            freqs, txp, rxp, xc, yc, zc, wsB, yr, yi, out, maxslot);
    else
        kirch_mfma<false><<<NVOX / 128, 256, 0, stream>>>(
            freqs, txp, rxp, xc, yc, zc, wsB, yr, yi, out, maxslot);

    int n4 = out_size / 4;
    normalize_kernel<<<(n4 + 255) / 256, 256, 0, stream>>>(out, maxslot, n4);
}